// Round 10
// baseline (30.560 us; speedup 1.0000x reference)
//
#include <hip/hip_runtime.h>
#include <math.h>

// MACE equivariant score head — 2-kernel form, v3 (z in-register inside K_B).
// Dead code: Wss (d_in[5]), Wvv (d_in[7]) — s3=silu(s2) is deleted in the reference.
//
// out[n,m] = sum_c vraw[n,c,m] * h[n,c],   h[n,c] = sum_u z[n,u] * E[u,c]
//   z[n,u] = t[n]*wtld[u] + sum_q feat[n,q] * W1s[16+q,u]
//   wtld[u]= sum_{p<16} Wt[p] * W1s[p,u]
//   E[u,c] = scale * sum_v D[u,v] * W1v[c,v],  D[u,v] = dot(Wsv[u,v,:], W2)
//   scale  = 1/(S*V*sqrt(V))   (all fan-in norms folded into E)
//
// K_A: 144 blocks, block u streams the contiguous 64KB slab Wsv[u,:,:] ->
//      D[u,:] (LDS) -> E[u,:].  Pure BW-bound, ~1.7us. (Verified in R8/R9.)
// K_B: 512 blocks x 8 rows (2 rows/wave). LDS = Esh 72KB + ubuf 4.5KB =
//      76.5KB -> 2 blocks/CU, 8 waves/CU. Per wave: z-GEMV with W~ rows
//      read from L2 (coalesced, latency hidden by 8 waves), z kept in regs,
//      s->z LDS overlay (within-wave DS ordering, no barrier), then h-GEMV
//      from Esh + register epilogue.

#define S 144
#define V 128

// ---------------- K_A: E[u,:] from Wsv slab u ----------------
__global__ __launch_bounds__(256) void kA_E(const float* __restrict__ Wsv,
                                            const float* __restrict__ W2,
                                            const float* __restrict__ W1v,
                                            float* __restrict__ E) {
    __shared__ float Dsh[V];
    __shared__ float Epart[2][V];
    const int tid = threadIdx.x;
    const int wave = tid >> 6;
    const int lane = tid & 63;
    const int half = lane >> 5;          // row within pair
    const int j = lane & 31;             // float4 index within 128-float row
    const int u = blockIdx.x;

    const float4* Wsv4 = (const float4*)Wsv;   // v-row stride = 32 float4
    const float4 w4 = ((const float4*)W2)[j];

    // D-phase: wave w covers v in [32w, 32w+32) as 16 row-pairs.
    const size_t base4 = ((size_t)u * V + 32 * wave) * 32;
    float4 a[16];
#pragma unroll
    for (int i = 0; i < 16; ++i)
        a[i] = Wsv4[base4 + (size_t)(2 * i + half) * 32 + j];

#pragma unroll
    for (int i = 0; i < 16; ++i) {
        float acc = a[i].x * w4.x + a[i].y * w4.y + a[i].z * w4.z + a[i].w * w4.w;
#pragma unroll
        for (int off = 1; off < 32; off <<= 1)
            acc += __shfl_xor(acc, off, 64);   // width-32: stays in half
        if (j == 0) Dsh[32 * wave + 2 * i + half] = acc;
    }
    __syncthreads();

    // E-phase: E[u,c] = scale * sum_v Dsh[v]*W1v[c,v]; thread = (c, v-half)
    const int c = tid & 127, vh = tid >> 7;
    const float4* W1v4 = (const float4*)W1v;
    const float4* D4 = (const float4*)Dsh;
    float acc = 0.f;
#pragma unroll
    for (int i = 0; i < 16; ++i) {
        const float4 wv = W1v4[c * 32 + vh * 16 + i];
        const float4 dv = D4[vh * 16 + i];
        acc += wv.x * dv.x + wv.y * dv.y + wv.z * dv.z + wv.w * dv.w;
    }
    Epart[vh][c] = acc;
    __syncthreads();
    if (tid < V) {
        const float scale = 1.0f / (144.0f * 128.0f * sqrtf(128.0f));
        E[u * V + tid] = scale * (Epart[0][tid] + Epart[1][tid]);
    }
}

// ---------------- K_B: z (regs, W~ from L2) -> h (Esh) -> epilogue ----------------
__global__ __launch_bounds__(256) void kB(const float* __restrict__ feat,
                                          const float* __restrict__ times,
                                          const float* __restrict__ Wt,
                                          const float* __restrict__ W1s,
                                          const float* __restrict__ Eg,
                                          float* __restrict__ out) {
    __shared__ float Esh[S * V];        // 72 KB
    __shared__ float ubuf[4][2][S];     // 4.5 KB: s (q=0..127) then z overlay (u=0..143)
    const int tid = threadIdx.x;
    const int wave = tid >> 6;
    const int lane = tid & 63;
    const int n0 = blockIdx.x * 8 + wave * 2;

    // (a) issue E staging early (HBM/L2 latency hides under z-phase)
    {
        const float4* src = (const float4*)Eg;
        float4* dst = (float4*)Esh;
#pragma unroll
        for (int k = 0; k < 18; ++k)
            dst[tid + 256 * k] = src[tid + 256 * k];
    }
    // (b) this wave's rows: vector part -> regs, scalar part -> ubuf
    float2 va[2][3];
#pragma unroll
    for (int r = 0; r < 2; ++r) {
        const float* p = feat + (size_t)(n0 + r) * 512 + V + 6 * lane;
        va[r][0] = *(const float2*)(p + 0);
        va[r][1] = *(const float2*)(p + 2);
        va[r][2] = *(const float2*)(p + 4);
    }
#pragma unroll
    for (int r = 0; r < 2; ++r) {
        const float2 sv = *(const float2*)(feat + (size_t)(n0 + r) * 512 + 2 * lane);
        *(float2*)&ubuf[wave][r][2 * lane] = sv;
    }
    float tval[2];
#pragma unroll
    for (int r = 0; r < 2; ++r) tval[r] = times[n0 + r];

    // (c) wtld slots for this lane's u = {lane, 64+lane, 128+lane(<16)}
    float wt_a = 0.f, wt_b = 0.f, wt_c = 0.f;
#pragma unroll
    for (int p = 0; p < 16; ++p) {
        const float w = Wt[p];
        const float* wr = W1s + (size_t)p * S;
        wt_a = fmaf(w, wr[lane], wt_a);
        wt_b = fmaf(w, wr[64 + lane], wt_b);
        if (lane < 16) wt_c = fmaf(w, wr[128 + lane], wt_c);
    }

    // (d) z-phase: z[r][u] in regs; W~ rows streamed from L2 (coalesced)
    float za[2], zb[2], zc[2];
#pragma unroll
    for (int r = 0; r < 2; ++r) {
        za[r] = tval[r] * wt_a;
        zb[r] = tval[r] * wt_b;
        zc[r] = tval[r] * wt_c;
    }
#pragma unroll 4
    for (int q = 0; q < 128; ++q) {
        const float* wr = W1s + (size_t)(16 + q) * S;
        const float wa = wr[lane];
        const float wb = wr[64 + lane];
        const float wc = (lane < 16) ? wr[128 + lane] : 0.f;
#pragma unroll
        for (int r = 0; r < 2; ++r) {
            const float sq = ubuf[wave][r][q];   // LDS broadcast (same-wave write)
            za[r] = fmaf(sq, wa, za[r]);
            zb[r] = fmaf(sq, wb, zb[r]);
            zc[r] = fmaf(sq, wc, zc[r]);
        }
    }
    // (e) overlay z into ubuf (same wave wrote & read s: DS ops are ordered)
#pragma unroll
    for (int r = 0; r < 2; ++r) {
        ubuf[wave][r][lane] = za[r];
        ubuf[wave][r][64 + lane] = zb[r];
        if (lane < 16) ubuf[wave][r][128 + lane] = zc[r];
    }

    __syncthreads();   // Esh fully staged (block-wide)

    // (f) h-phase: h[r][c=2l,2l+1] = sum_u z[r][u] * E[u,c]
    float h0[2] = {0.f, 0.f};
    float h1[2] = {0.f, 0.f};
#pragma unroll 4
    for (int u = 0; u < S; ++u) {
        const float2 m2 = *(const float2*)&Esh[u * V + 2 * lane];
#pragma unroll
        for (int r = 0; r < 2; ++r) {
            const float zu = ubuf[wave][r][u];    // LDS broadcast
            h0[r] = fmaf(zu, m2.x, h0[r]);
            h1[r] = fmaf(zu, m2.y, h1[r]);
        }
    }

    // (g) epilogue: lane l holds c=2l (va[0].x, va[0].y, va[1].x)
    // and c=2l+1 (va[1].y, va[2].x, va[2].y)
#pragma unroll
    for (int r = 0; r < 2; ++r) {
        float pm0 = va[r][0].x * h0[r] + va[r][1].y * h1[r];
        float pm1 = va[r][0].y * h0[r] + va[r][2].x * h1[r];
        float pm2 = va[r][1].x * h0[r] + va[r][2].y * h1[r];
#pragma unroll
        for (int off = 1; off < 64; off <<= 1) {
            pm0 += __shfl_xor(pm0, off, 64);
            pm1 += __shfl_xor(pm1, off, 64);
            pm2 += __shfl_xor(pm2, off, 64);
        }
        if (lane == 0) {
            out[(n0 + r) * 3 + 0] = pm0;
            out[(n0 + r) * 3 + 1] = pm1;
            out[(n0 + r) * 3 + 2] = pm2;
        }
    }
}

extern "C" void kernel_launch(void* const* d_in, const int* in_sizes, int n_in,
                              void* d_out, int out_size, void* d_ws, size_t ws_size,
                              hipStream_t stream) {
    const float* feat  = (const float*)d_in[0];  // [4096, 512]
    const float* times = (const float*)d_in[1];  // [4096, 1]
    const float* Wt    = (const float*)d_in[2];  // [1,16]
    const float* W1s   = (const float*)d_in[3];  // [144,144]
    const float* W1v   = (const float*)d_in[4];  // [128,128]
    // d_in[5] = Wss  -- dead path
    const float* Wsv   = (const float*)d_in[6];  // [144,128,128]
    // d_in[7] = Wvv  -- dead path
    const float* W2    = (const float*)d_in[8];  // [128,1]

    float* E = (float*)d_ws;   // 18432 f32

    kA_E<<<dim3(144), dim3(256), 0, stream>>>(Wsv, W2, W1v, E);
    kB<<<dim3(512), dim3(256), 0, stream>>>(feat, times, Wt, W1s, E, (float*)d_out);
}

// Round 11
// 26.122 us; speedup vs baseline: 1.1699x; 1.1699x over previous
//
#include <hip/hip_runtime.h>
#include <math.h>

// MACE equivariant score head — 2-kernel form, v4 (E-blocks ∥ Z-blocks in kA).
// Dead code: Wss (d_in[5]), Wvv (d_in[7]) — s3=silu(s2) is deleted in the reference.
//
// out[n,m] = sum_c vraw[n,c,m] * h[n,c],   h[n,c] = sum_u z[n,u] * E[u,c]
//   z[n,u] = t[n]*wtld[u] + sum_q feat[n,q] * W1s[16+q,u]
//   wtld[u]= sum_{p<16} Wt[p] * W1s[p,u]
//   E[u,c] = scale * sum_v D[u,v] * W1v[c,v],  D[u,v] = dot(Wsv[u,v,:], W2)
//   scale  = 1/(S*V*sqrt(V))   (all fan-in norms folded into E)
//
// kA: 656 blocks.
//   [0,144): E-block u — streams contiguous 64KB slab Wsv[u,:,:] -> D[u,:]
//            (LDS) -> E[u,:]. HBM-bound (9.4MB total). Verified R8-R10.
//   [144,656): Z-block — 8 rows. W~ = W1s[16:144,:] staged LINEARLY in LDS
//            (73.7KB, contiguous float4 copy); z-GEMV reads are stride-1
//            conflict-free b32; LDS total 78.4KB -> 2 blocks/CU, 8 waves/CU.
//            Overlaps the E-blocks' HBM stream (disjoint pipes).
// kB: 512 blocks x 8 rows (2 rows/wave). Esh 72KB + zbuf 4.6KB = 76.6KB ->
//     2 blocks/CU. h-GEMV (b64 E reads, 2-way free) + register epilogue.

#define S 144
#define V 128

// ---------------- kA: E-blocks + Z-blocks ----------------
__global__ __launch_bounds__(256) void kA(const float* __restrict__ feat,
                                          const float* __restrict__ times,
                                          const float* __restrict__ Wt,
                                          const float* __restrict__ W1s,
                                          const float* __restrict__ W1v,
                                          const float* __restrict__ Wsv,
                                          const float* __restrict__ W2,
                                          float* __restrict__ E,
                                          float* __restrict__ Z) {
    // one pool, aliased by both paths: 18432 + 1024 + 144 floats = 78.4 KB
    __shared__ float smem[S * V + 1024 + S];
    const int tid = threadIdx.x;
    const int wave = tid >> 6;
    const int lane = tid & 63;

    if (blockIdx.x < S) {
        // ---- E-block: u = blockIdx.x ----
        float* Dsh = smem;              // 128
        float* Epart = smem + V;        // 2*128
        const int half = lane >> 5;
        const int j = lane & 31;
        const int u = blockIdx.x;
        const float4* Wsv4 = (const float4*)Wsv;
        const float4 w4 = ((const float4*)W2)[j];
        const size_t base4 = ((size_t)u * V + 32 * wave) * 32;
        float4 a[16];
#pragma unroll
        for (int i = 0; i < 16; ++i)
            a[i] = Wsv4[base4 + (size_t)(2 * i + half) * 32 + j];
#pragma unroll
        for (int i = 0; i < 16; ++i) {
            float acc = a[i].x * w4.x + a[i].y * w4.y + a[i].z * w4.z + a[i].w * w4.w;
#pragma unroll
            for (int off = 1; off < 32; off <<= 1)
                acc += __shfl_xor(acc, off, 64);   // width-32: stays in half
            if (j == 0) Dsh[32 * wave + 2 * i + half] = acc;
        }
        __syncthreads();
        // E[u,c] = scale * sum_v Dsh[v]*W1v[c,v]; thread = (c, v-half)
        const int c = tid & 127, vh = tid >> 7;
        const float4* W1v4 = (const float4*)W1v;
        const float4* D4 = (const float4*)Dsh;
        float acc = 0.f;
#pragma unroll
        for (int i = 0; i < 16; ++i) {
            const float4 wv = W1v4[c * 32 + vh * 16 + i];
            const float4 dv = D4[vh * 16 + i];
            acc += wv.x * dv.x + wv.y * dv.y + wv.z * dv.z + wv.w * dv.w;
        }
        Epart[vh * V + c] = acc;
        __syncthreads();
        if (tid < V) {
            const float scale = 1.0f / (144.0f * 128.0f * sqrtf(128.0f));
            E[u * V + tid] = scale * (Epart[tid] + Epart[V + tid]);
        }
    } else {
        // ---- Z-block: 8 rows, W~ staged linearly in LDS ----
        float* Wq = smem;                    // [128*144] = W1s[16+q, u] (linear copy)
        float* srow = smem + S * V;          // [4][2][128]
        float* wtld = smem + S * V + 1024;   // [144]
        const int n0 = (int)(blockIdx.x - S) * 8 + wave * 2;

        // stage W~ (contiguous 18432 floats = 4608 float4)
        {
            const float4* src = (const float4*)(W1s + 16 * S);
            float4* dst = (float4*)Wq;
#pragma unroll
            for (int k = 0; k < 18; ++k)
                dst[tid + 256 * k] = src[tid + 256 * k];
        }
        // scalar rows -> srow (coalesced float2)
#pragma unroll
        for (int r = 0; r < 2; ++r) {
            const float2 sv = *(const float2*)(feat + (size_t)(n0 + r) * 512 + 2 * lane);
            *(float2*)&srow[(wave * 2 + r) * V + 2 * lane] = sv;
        }
        // wtld[u] = sum_{p<16} Wt[p]*W1s[p,u]
        if (tid < S) {
            float acc = 0.f;
#pragma unroll
            for (int p = 0; p < 16; ++p)
                acc = fmaf(Wt[p], W1s[p * S + tid], acc);
            wtld[tid] = acc;
        }
        float tval[2];
#pragma unroll
        for (int r = 0; r < 2; ++r) tval[r] = times[n0 + r];
        __syncthreads();

        // z-GEMV: lane owns u = {lane, 64+lane, 128+lane(<16)}
        const float wt_a = wtld[lane];
        const float wt_b = wtld[64 + lane];
        const float wt_c = (lane < 16) ? wtld[128 + lane] : 0.f;
        float za[2], zb[2], zc[2];
#pragma unroll
        for (int r = 0; r < 2; ++r) {
            za[r] = tval[r] * wt_a;
            zb[r] = tval[r] * wt_b;
            zc[r] = tval[r] * wt_c;
        }
#pragma unroll 4
        for (int q = 0; q < 128; ++q) {
            const float* wr = Wq + q * S;
            const float wa = wr[lane];           // stride-1 across lanes: conflict-free
            const float wb = wr[64 + lane];
            const float wc = (lane < 16) ? wr[128 + lane] : 0.f;
#pragma unroll
            for (int r = 0; r < 2; ++r) {
                const float sq = srow[(wave * 2 + r) * V + q];   // broadcast
                za[r] = fmaf(sq, wa, za[r]);
                zb[r] = fmaf(sq, wb, zb[r]);
                zc[r] = fmaf(sq, wc, zc[r]);
            }
        }
        // write Z (coalesced: u = lane stride-1)
#pragma unroll
        for (int r = 0; r < 2; ++r) {
            const int n = n0 + r;
            Z[(size_t)n * S + lane] = za[r];
            Z[(size_t)n * S + 64 + lane] = zb[r];
            if (lane < 16) Z[(size_t)n * S + 128 + lane] = zc[r];
        }
    }
}

// ---------------- kB: h = z.E + epilogue ----------------
// 512 blocks x 256 thr (4 waves), 8 rows/block, 2 rows/wave.
__global__ __launch_bounds__(256) void kB(const float* __restrict__ feat,
                                          const float* __restrict__ Zg,
                                          const float* __restrict__ Eg,
                                          float* __restrict__ out) {
    __shared__ float Esh[S * V];        // 72 KB
    __shared__ float zbuf[4][2][S];     // 4.6 KB
    const int tid = threadIdx.x;
    const int wave = tid >> 6;
    const int lane = tid & 63;
    const int n0 = blockIdx.x * 8 + wave * 2;

    // vector part of this wave's 2 rows -> regs (lane owns channels 2l, 2l+1)
    float2 va[2][3];
#pragma unroll
    for (int r = 0; r < 2; ++r) {
        const float* p = feat + (size_t)(n0 + r) * 512 + V + 6 * lane;
        va[r][0] = *(const float2*)(p + 0);
        va[r][1] = *(const float2*)(p + 2);
        va[r][2] = *(const float2*)(p + 4);
    }
    // z rows -> LDS (144 floats = 36 float4 per row)
#pragma unroll
    for (int r = 0; r < 2; ++r) {
        if (lane < 36) {
            const float4 zv = ((const float4*)(Zg + (size_t)(n0 + r) * S))[lane];
            *(float4*)&zbuf[wave][r][4 * lane] = zv;
        }
    }
    // cooperative E load: 18432 f32 = 4608 float4 / 256 thr
    {
        const float4* src = (const float4*)Eg;
        float4* dst = (float4*)Esh;
#pragma unroll
        for (int k = 0; k < 18; ++k)
            dst[tid + 256 * k] = src[tid + 256 * k];
    }
    __syncthreads();

    // h[r][c=2l,2l+1] = sum_u z[r][u] * E[u,c]
    float h0[2] = {0.f, 0.f};
    float h1[2] = {0.f, 0.f};
#pragma unroll 4
    for (int u = 0; u < S; ++u) {
        const float2 m2 = *(const float2*)&Esh[u * V + 2 * lane];
#pragma unroll
        for (int r = 0; r < 2; ++r) {
            const float zu = zbuf[wave][r][u];    // LDS broadcast
            h0[r] = fmaf(zu, m2.x, h0[r]);
            h1[r] = fmaf(zu, m2.y, h1[r]);
        }
    }

    // epilogue: lane l holds c=2l (va[0].x, va[0].y, va[1].x)
    // and c=2l+1 (va[1].y, va[2].x, va[2].y)
#pragma unroll
    for (int r = 0; r < 2; ++r) {
        float pm0 = va[r][0].x * h0[r] + va[r][1].y * h1[r];
        float pm1 = va[r][0].y * h0[r] + va[r][2].x * h1[r];
        float pm2 = va[r][1].x * h0[r] + va[r][2].y * h1[r];
#pragma unroll
        for (int off = 1; off < 64; off <<= 1) {
            pm0 += __shfl_xor(pm0, off, 64);
            pm1 += __shfl_xor(pm1, off, 64);
            pm2 += __shfl_xor(pm2, off, 64);
        }
        if (lane == 0) {
            out[(n0 + r) * 3 + 0] = pm0;
            out[(n0 + r) * 3 + 1] = pm1;
            out[(n0 + r) * 3 + 2] = pm2;
        }
    }
}

extern "C" void kernel_launch(void* const* d_in, const int* in_sizes, int n_in,
                              void* d_out, int out_size, void* d_ws, size_t ws_size,
                              hipStream_t stream) {
    const float* feat  = (const float*)d_in[0];  // [4096, 512]
    const float* times = (const float*)d_in[1];  // [4096, 1]
    const float* Wt    = (const float*)d_in[2];  // [1,16]
    const float* W1s   = (const float*)d_in[3];  // [144,144]
    const float* W1v   = (const float*)d_in[4];  // [128,128]
    // d_in[5] = Wss  -- dead path
    const float* Wsv   = (const float*)d_in[6];  // [144,128,128]
    // d_in[7] = Wvv  -- dead path
    const float* W2    = (const float*)d_in[8];  // [128,1]

    float* E = (float*)d_ws;          // 18432 f32
    float* Z = E + S * V;             // 4096*144 f32 (2.36 MB)

    kA<<<dim3(656), dim3(256), 0, stream>>>(feat, times, Wt, W1s, W1v, Wsv, W2, E, Z);
    kB<<<dim3(512), dim3(256), 0, stream>>>(feat, Z, E, (float*)d_out);
}

// Round 12
// 26.083 us; speedup vs baseline: 1.1716x; 1.0015x over previous
//
#include <hip/hip_runtime.h>
#include <math.h>

// MACE equivariant score head — 2-kernel form, v5 (co-resident E∥Z, tiny LDS).
// Dead code: Wss (d_in[5]), Wvv (d_in[7]) — s3=silu(s2) is deleted in the reference.
//
// out[n,m] = sum_c vraw[n,c,m] * h[n,c],   h[n,c] = sum_u z[n,u] * E[u,c]
//   z[n,u] = t[n]*wtld[u] + sum_q feat[n,q] * W1s[16+q,u]
//   wtld[u]= sum_{p<16} Wt[p] * W1s[p,u]
//   E[u,c] = scale * sum_v D[u,v] * W1v[c,v],  D[u,v] = dot(Wsv[u,v,:], W2)
//   scale  = 1/(S*V*sqrt(V))   (all fan-in norms folded into E)
//
// kA: 400 blocks, ALL small-LDS (<=8.6KB) so every block is co-resident:
//   [0,144): E-block u — streams contiguous 64KB slab Wsv[u,:,:] -> D[u,:]
//            (LDS) -> E[u,:]. HBM-bound. (Verified R8-R11.)
//   [144,400): Z-block — 16 rows, 4 rows/wave. W~ rows read DIRECTLY from
//            L2 (no LDS staging; 1024 waves x 73.7KB = 75MB L2 ~= 2.2us
//            aggregate), s via LDS broadcast. VALU-bound, overlaps the
//            E-blocks' HBM stream.
// kB: 512 blocks x 8 rows (2 rows/wave). Esh 72KB + zbuf 4.6KB -> 2 blocks/CU,
//     8 waves/CU. h-GEMV (b64 E reads, 2-way free) + register epilogue.
//     (Verified shape R9/R11.)

#define S 144
#define V 128

// ---------------- kA: E-blocks + Z-blocks (all co-resident) ----------------
__global__ __launch_bounds__(256) void kA(const float* __restrict__ feat,
                                          const float* __restrict__ times,
                                          const float* __restrict__ Wt,
                                          const float* __restrict__ W1s,
                                          const float* __restrict__ W1v,
                                          const float* __restrict__ Wsv,
                                          const float* __restrict__ W2,
                                          float* __restrict__ E,
                                          float* __restrict__ Z) {
    // shared pool: E path uses 384 floats; Z path uses 16*128 + 144 floats.
    __shared__ float smem[16 * V + S];   // 8.8 KB
    const int tid = threadIdx.x;
    const int wave = tid >> 6;
    const int lane = tid & 63;

    if (blockIdx.x < S) {
        // ---- E-block: u = blockIdx.x ----
        float* Dsh = smem;              // [128]
        float* Epart = smem + V;        // [2][128]
        const int half = lane >> 5;
        const int j = lane & 31;
        const int u = blockIdx.x;
        const float4* Wsv4 = (const float4*)Wsv;
        const float4 w4 = ((const float4*)W2)[j];
        const size_t base4 = ((size_t)u * V + 32 * wave) * 32;
        float4 a[16];
#pragma unroll
        for (int i = 0; i < 16; ++i)
            a[i] = Wsv4[base4 + (size_t)(2 * i + half) * 32 + j];
#pragma unroll
        for (int i = 0; i < 16; ++i) {
            float acc = a[i].x * w4.x + a[i].y * w4.y + a[i].z * w4.z + a[i].w * w4.w;
#pragma unroll
            for (int off = 1; off < 32; off <<= 1)
                acc += __shfl_xor(acc, off, 64);   // width-32: stays in half
            if (j == 0) Dsh[32 * wave + 2 * i + half] = acc;
        }
        __syncthreads();
        // E[u,c] = scale * sum_v Dsh[v]*W1v[c,v]; thread = (c, v-half)
        const int c = tid & 127, vh = tid >> 7;
        const float4* W1v4 = (const float4*)W1v;
        const float4* D4 = (const float4*)Dsh;
        float acc = 0.f;
#pragma unroll
        for (int i = 0; i < 16; ++i) {
            const float4 wv = W1v4[c * 32 + vh * 16 + i];
            const float4 dv = D4[vh * 16 + i];
            acc += wv.x * dv.x + wv.y * dv.y + wv.z * dv.z + wv.w * dv.w;
        }
        Epart[vh * V + c] = acc;
        __syncthreads();
        if (tid < V) {
            const float scale = 1.0f / (144.0f * 128.0f * sqrtf(128.0f));
            E[u * V + tid] = scale * (Epart[tid] + Epart[V + tid]);
        }
    } else {
        // ---- Z-block: 16 rows, 4 rows/wave; W~ streamed from L2 ----
        float* srow = smem;              // [16][128]
        float* wtld = smem + 16 * V;     // [144]
        const int n0 = (int)(blockIdx.x - S) * 16;

        // stage scalar rows (wave w: rows 4w..4w+3), coalesced float2
#pragma unroll
        for (int r = 0; r < 4; ++r) {
            const int row = wave * 4 + r;
            const float2 sv = *(const float2*)(feat + (size_t)(n0 + row) * 512 + 2 * lane);
            *(float2*)&srow[row * V + 2 * lane] = sv;
        }
        // wtld[u] = sum_{p<16} Wt[p]*W1s[p,u]
        if (tid < S) {
            float acc = 0.f;
#pragma unroll
            for (int p = 0; p < 16; ++p)
                acc = fmaf(Wt[p], W1s[p * S + tid], acc);
            wtld[tid] = acc;
        }
        __syncthreads();

        // lane owns u = {lane, 64+lane, 128+lane(<16)}; 4 rows per wave
        const float wt_a = wtld[lane];
        const float wt_b = wtld[64 + lane];
        const float wt_c = (lane < 16) ? wtld[128 + lane] : 0.f;
        float tv[4];
#pragma unroll
        for (int r = 0; r < 4; ++r) tv[r] = times[n0 + wave * 4 + r];
        float za[4], zb[4], zc[4];
#pragma unroll
        for (int r = 0; r < 4; ++r) {
            za[r] = tv[r] * wt_a;
            zb[r] = tv[r] * wt_b;
            zc[r] = tv[r] * wt_c;
        }
#pragma unroll 4
        for (int q = 0; q < 128; ++q) {
            const float* wr = W1s + (size_t)(16 + q) * S;
            const float wa = wr[lane];                      // L2, coalesced
            const float wb = wr[64 + lane];
            const float wc = (lane < 16) ? wr[128 + lane] : 0.f;
#pragma unroll
            for (int r = 0; r < 4; ++r) {
                const float sq = srow[(wave * 4 + r) * V + q];   // LDS broadcast
                za[r] = fmaf(sq, wa, za[r]);
                zb[r] = fmaf(sq, wb, zb[r]);
                zc[r] = fmaf(sq, wc, zc[r]);
            }
        }
        // write Z (coalesced: u = lane stride-1)
#pragma unroll
        for (int r = 0; r < 4; ++r) {
            const int n = n0 + wave * 4 + r;
            Z[(size_t)n * S + lane] = za[r];
            Z[(size_t)n * S + 64 + lane] = zb[r];
            if (lane < 16) Z[(size_t)n * S + 128 + lane] = zc[r];
        }
    }
}

// ---------------- kB: h = z.E + epilogue ----------------
// 512 blocks x 256 thr (4 waves), 8 rows/block, 2 rows/wave.
__global__ __launch_bounds__(256) void kB(const float* __restrict__ feat,
                                          const float* __restrict__ Zg,
                                          const float* __restrict__ Eg,
                                          float* __restrict__ out) {
    __shared__ float Esh[S * V];        // 72 KB
    __shared__ float zbuf[4][2][S];     // 4.6 KB
    const int tid = threadIdx.x;
    const int wave = tid >> 6;
    const int lane = tid & 63;
    const int n0 = blockIdx.x * 8 + wave * 2;

    // vector part of this wave's 2 rows -> regs (lane owns channels 2l, 2l+1)
    float2 va[2][3];
#pragma unroll
    for (int r = 0; r < 2; ++r) {
        const float* p = feat + (size_t)(n0 + r) * 512 + V + 6 * lane;
        va[r][0] = *(const float2*)(p + 0);
        va[r][1] = *(const float2*)(p + 2);
        va[r][2] = *(const float2*)(p + 4);
    }
    // z rows -> LDS (144 floats = 36 float4 per row)
#pragma unroll
    for (int r = 0; r < 2; ++r) {
        if (lane < 36) {
            const float4 zv = ((const float4*)(Zg + (size_t)(n0 + r) * S))[lane];
            *(float4*)&zbuf[wave][r][4 * lane] = zv;
        }
    }
    // cooperative E load: 18432 f32 = 4608 float4 / 256 thr
    {
        const float4* src = (const float4*)Eg;
        float4* dst = (float4*)Esh;
#pragma unroll
        for (int k = 0; k < 18; ++k)
            dst[tid + 256 * k] = src[tid + 256 * k];
    }
    __syncthreads();

    // h[r][c=2l,2l+1] = sum_u z[r][u] * E[u,c]
    float h0[2] = {0.f, 0.f};
    float h1[2] = {0.f, 0.f};
#pragma unroll 4
    for (int u = 0; u < S; ++u) {
        const float2 m2 = *(const float2*)&Esh[u * V + 2 * lane];
#pragma unroll
        for (int r = 0; r < 2; ++r) {
            const float zu = zbuf[wave][r][u];    // LDS broadcast
            h0[r] = fmaf(zu, m2.x, h0[r]);
            h1[r] = fmaf(zu, m2.y, h1[r]);
        }
    }

    // epilogue: lane l holds c=2l (va[0].x, va[0].y, va[1].x)
    // and c=2l+1 (va[1].y, va[2].x, va[2].y)
#pragma unroll
    for (int r = 0; r < 2; ++r) {
        float pm0 = va[r][0].x * h0[r] + va[r][1].y * h1[r];
        float pm1 = va[r][0].y * h0[r] + va[r][2].x * h1[r];
        float pm2 = va[r][1].x * h0[r] + va[r][2].y * h1[r];
#pragma unroll
        for (int off = 1; off < 64; off <<= 1) {
            pm0 += __shfl_xor(pm0, off, 64);
            pm1 += __shfl_xor(pm1, off, 64);
            pm2 += __shfl_xor(pm2, off, 64);
        }
        if (lane == 0) {
            out[(n0 + r) * 3 + 0] = pm0;
            out[(n0 + r) * 3 + 1] = pm1;
            out[(n0 + r) * 3 + 2] = pm2;
        }
    }
}

extern "C" void kernel_launch(void* const* d_in, const int* in_sizes, int n_in,
                              void* d_out, int out_size, void* d_ws, size_t ws_size,
                              hipStream_t stream) {
    const float* feat  = (const float*)d_in[0];  // [4096, 512]
    const float* times = (const float*)d_in[1];  // [4096, 1]
    const float* Wt    = (const float*)d_in[2];  // [1,16]
    const float* W1s   = (const float*)d_in[3];  // [144,144]
    const float* W1v   = (const float*)d_in[4];  // [128,128]
    // d_in[5] = Wss  -- dead path
    const float* Wsv   = (const float*)d_in[6];  // [144,128,128]
    // d_in[7] = Wvv  -- dead path
    const float* W2    = (const float*)d_in[8];  // [128,1]

    float* E = (float*)d_ws;          // 18432 f32
    float* Z = E + S * V;             // 4096*144 f32 (2.36 MB)

    kA<<<dim3(400), dim3(256), 0, stream>>>(feat, times, Wt, W1s, W1v, Wsv, W2, E, Z);
    kB<<<dim3(512), dim3(256), 0, stream>>>(feat, Z, E, (float*)d_out);
}

// Round 13
// 18.708 us; speedup vs baseline: 1.6335x; 1.3942x over previous
//
#include <hip/hip_runtime.h>
#include <hip/hip_bf16.h>
#include <math.h>

// MACE equivariant score head — 3-kernel M-form, K4 rebuilt on bf16 MFMA.
// Dead code: Wss (d_in[5]), Wvv (d_in[7]) — s3=silu(s2) is deleted in the reference.
// out[n,m] = sum_c vraw[n,c,m] * h[n,c]
// h[n,c]   = t[n]*b[c] + sum_q feat[n,q] * M[q,c]
//   D[u,v] = dot(Wsv[u,v,:], W2); F[v] = sum_u wrow[u] D[u,v]
//   M[q,c] = scale * sum_v F[v] * W1v[c,v],  scale = 1/(S*V*sqrt(V))
// K23 stores M TRANSPOSED in bf16: Mt[c][q]  (B-operand layout for MFMA).
// K4: 256 blocks x 16 rows; h-GEMM via mfma_f32_16x16x32_bf16:
//   A[m=row 0..15][k=q] = s (bf16, LDS padded), B[k=q][n=c] = Mt (bf16, LDS padded).
//   Per wave: 4 k-steps x (1 A b128 + 2 B b128 + 2 MFMA) — ~15x fewer LDS instrs
//   than the f32 FMA version (which was LDS-pipe-bound at ~5.5us).

#define S 144
#define V 128

typedef __attribute__((ext_vector_type(8))) short bf16x8;
typedef __attribute__((ext_vector_type(4))) float f32x4;

// ---------------- K1: D[u*V+v] = dot(Wsv[u,v,:], W2) ----------------
__global__ __launch_bounds__(256) void k1_D(const float* __restrict__ Wsv,
                                            const float* __restrict__ W2,
                                            float* __restrict__ D) {
    const int wave = threadIdx.x >> 6;
    const int lane = threadIdx.x & 63;
    const int uv = blockIdx.x * 4 + wave;
    const float2* src = (const float2*)Wsv + (size_t)uv * 64;
    const float2* w2 = (const float2*)W2;
    float2 a = src[lane];
    float2 w = w2[lane];
    float acc = a.x * w.x + a.y * w.y;
#pragma unroll
    for (int off = 1; off < 64; off <<= 1)
        acc += __shfl_xor(acc, off, 64);
    if (lane == 0) D[uv] = acc;
}

// ---------------- K23: per-block row of M (bf16, transposed) or b ----------------
__global__ __launch_bounds__(256) void k23_Mb(const float* __restrict__ D,
                                              const float* __restrict__ W1s,
                                              const float* __restrict__ W1v,
                                              const float* __restrict__ Wt,
                                              unsigned short* __restrict__ Mt,
                                              float* __restrict__ b) {
    __shared__ float w1v[V * 129];     // 66 KB, +1 pad
    __shared__ float wrow[S];
    __shared__ float Fpart[4][V];
    __shared__ float Fsh[V];
    const int tid = threadIdx.x;
    const int q = blockIdx.x;

    {
        const float4* W1v4 = (const float4*)W1v;
        for (int i = tid; i < V * V / 4; i += 256) {
            const float4 t = W1v4[i];
            const int base = i * 4;
            float* dst = &w1v[(base >> 7) * 129 + (base & 127)];
            dst[0] = t.x; dst[1] = t.y; dst[2] = t.z; dst[3] = t.w;
        }
    }
    if (tid < S) {
        if (q < V) {
            wrow[tid] = W1s[(16 + q) * S + tid];
        } else {
            float acc = 0.f;
#pragma unroll
            for (int p = 0; p < 16; ++p)
                acc = fmaf(Wt[p], W1s[p * S + tid], acc);
            wrow[tid] = acc;
        }
    }
    __syncthreads();

    {
        const int w = tid >> 6, t = tid & 63;
        float fx = 0.f, fy = 0.f;
#pragma unroll 6
        for (int u = 36 * w; u < 36 * w + 36; ++u) {
            const float wr = wrow[u];
            const float2 dv = *(const float2*)&D[u * V + 2 * t];
            fx = fmaf(wr, dv.x, fx);
            fy = fmaf(wr, dv.y, fy);
        }
        Fpart[w][2 * t + 0] = fx;
        Fpart[w][2 * t + 1] = fy;
    }
    __syncthreads();
    if (tid < V)
        Fsh[tid] = (Fpart[0][tid] + Fpart[1][tid]) + (Fpart[2][tid] + Fpart[3][tid]);
    __syncthreads();

    if (tid < V) {
        const float scale = 1.0f / (144.0f * 128.0f * sqrtf(128.0f));
        float m0 = 0.f, m1 = 0.f, m2 = 0.f, m3 = 0.f;
#pragma unroll 8
        for (int v = 0; v < V; v += 4) {
            m0 = fmaf(Fsh[v + 0], w1v[tid * 129 + v + 0], m0);
            m1 = fmaf(Fsh[v + 1], w1v[tid * 129 + v + 1], m1);
            m2 = fmaf(Fsh[v + 2], w1v[tid * 129 + v + 2], m2);
            m3 = fmaf(Fsh[v + 3], w1v[tid * 129 + v + 3], m3);
        }
        const float r = ((m0 + m1) + (m2 + m3)) * scale;
        if (q < V) {
            const __hip_bfloat16 h = __float2bfloat16(r);
            Mt[tid * V + q] = *(const unsigned short*)&h;   // transposed bf16
        } else {
            b[tid] = r;
        }
    }
}

// ---------------- K4: MFMA h-GEMM + epilogue ----------------
// 256 blocks x 256 thr (4 waves), 16 rows/block. Wave w owns c in [32w,32w+32).
__global__ __launch_bounds__(256) void k4_mfma(const float* __restrict__ feat,
                                               const float* __restrict__ times,
                                               const unsigned short* __restrict__ Mtg,
                                               const float* __restrict__ bg,
                                               float* __restrict__ out) {
    __shared__ unsigned short Msh[V][136];   // bf16, +8 bf16 (16B) row pad
    __shared__ unsigned short srow[16][136]; // bf16 s rows, same pad
    __shared__ float tsh[16];
    __shared__ float red[4][16][3];
    const int tid = threadIdx.x;
    const int wave = tid >> 6;
    const int lane = tid & 63;
    const int n0 = blockIdx.x * 16;

    // stage Mt (16384 bf16 = 2048 uint4), 8 uint4/thread, into padded rows
    {
        const uint4* src = (const uint4*)Mtg;
#pragma unroll
        for (int i = 0; i < 8; ++i) {
            const int idx = tid + 256 * i;       // uint4 index
            const int r = idx >> 4;              // 16 uint4 per 128-bf16 row
            const int c8 = (idx & 15) * 8;       // bf16 col
            *(uint4*)&Msh[r][c8] = src[idx];
        }
    }
    // stage s rows as bf16: thread -> row tid>>4, q0 = (tid&15)*8
    {
        const int r = tid >> 4, q0 = (tid & 15) * 8;
        const float* p = feat + (size_t)(n0 + r) * 512 + q0;
        const float4 f0 = *(const float4*)(p);
        const float4 f1 = *(const float4*)(p + 4);
        __hip_bfloat162 p0 = __float22bfloat162_rn(make_float2(f0.x, f0.y));
        __hip_bfloat162 p1 = __float22bfloat162_rn(make_float2(f0.z, f0.w));
        __hip_bfloat162 p2 = __float22bfloat162_rn(make_float2(f1.x, f1.y));
        __hip_bfloat162 p3 = __float22bfloat162_rn(make_float2(f1.z, f1.w));
        uint4 pk;
        pk.x = *(const unsigned*)&p0;
        pk.y = *(const unsigned*)&p1;
        pk.z = *(const unsigned*)&p2;
        pk.w = *(const unsigned*)&p3;
        *(uint4*)&srow[r][q0] = pk;
    }
    if (tid < 16) tsh[tid] = times[n0 + tid];
    // per-lane bias values for its two c's
    const int mrow = lane & 15;     // A-row / B-col within tile / C-col
    const int kch = lane >> 4;      // k-chunk 0..3
    const float bc0 = bg[32 * wave + mrow];
    const float bc1 = bg[32 * wave + 16 + mrow];
    __syncthreads();

    // MFMA: A = s[16 x 128], B = M[128 x 128] restricted to wave's 32 cols
    f32x4 acc0 = {0.f, 0.f, 0.f, 0.f};
    f32x4 acc1 = {0.f, 0.f, 0.f, 0.f};
#pragma unroll
    for (int kk = 0; kk < 4; ++kk) {
        const bf16x8 af = *(const bf16x8*)&srow[mrow][kk * 32 + kch * 8];
        const bf16x8 bf0 = *(const bf16x8*)&Msh[32 * wave + mrow][kk * 32 + kch * 8];
        const bf16x8 bf1 = *(const bf16x8*)&Msh[32 * wave + 16 + mrow][kk * 32 + kch * 8];
        acc0 = __builtin_amdgcn_mfma_f32_16x16x32_bf16(af, bf0, acc0, 0, 0, 0);
        acc1 = __builtin_amdgcn_mfma_f32_16x16x32_bf16(af, bf1, acc1, 0, 0, 0);
    }

    // epilogue: lane holds h[n=(lane>>4)*4+i][c0=32w+mrow] (acc0) and c1=c0+16 (acc1)
    float pm[4][3];
#pragma unroll
    for (int i = 0; i < 4; ++i) {
        const int nr = kch * 4 + i;
        const float t = tsh[nr];
        const float h0 = acc0[i] + t * bc0;
        const float h1 = acc1[i] + t * bc1;
        const float* vp0 = feat + (size_t)(n0 + nr) * 512 + V + 3 * (32 * wave + mrow);
        const float* vp1 = vp0 + 48;   // c1 = c0 + 16 -> +48 floats
#pragma unroll
        for (int m = 0; m < 3; ++m)
            pm[i][m] = vp0[m] * h0 + vp1[m] * h1;
    }
    // reduce over the 16-lane c-group (offsets < 16 stay in group)
#pragma unroll
    for (int i = 0; i < 4; ++i) {
#pragma unroll
        for (int m = 0; m < 3; ++m) {
            float v = pm[i][m];
            v += __shfl_xor(v, 1, 64);
            v += __shfl_xor(v, 2, 64);
            v += __shfl_xor(v, 4, 64);
            v += __shfl_xor(v, 8, 64);
            pm[i][m] = v;
        }
        if (mrow == 0) {
            const int nr = kch * 4 + i;
            red[wave][nr][0] = pm[i][0];
            red[wave][nr][1] = pm[i][1];
            red[wave][nr][2] = pm[i][2];
        }
    }
    __syncthreads();
    // sum the 4 wave-partials (c-blocks) and write out
    if (tid < 48) {
        const int nr = tid / 3, m = tid % 3;
        out[(size_t)(n0 + nr) * 3 + m] =
            red[0][nr][m] + red[1][nr][m] + red[2][nr][m] + red[3][nr][m];
    }
}

extern "C" void kernel_launch(void* const* d_in, const int* in_sizes, int n_in,
                              void* d_out, int out_size, void* d_ws, size_t ws_size,
                              hipStream_t stream) {
    const float* feat  = (const float*)d_in[0];  // [4096, 512]
    const float* times = (const float*)d_in[1];  // [4096, 1]
    const float* Wt    = (const float*)d_in[2];  // [1,16]
    const float* W1s   = (const float*)d_in[3];  // [144,144]
    const float* W1v   = (const float*)d_in[4];  // [128,128]
    // d_in[5] = Wss  -- dead path
    const float* Wsv   = (const float*)d_in[6];  // [144,128,128]
    // d_in[7] = Wvv  -- dead path
    const float* W2    = (const float*)d_in[8];  // [128,1]

    float* ws = (float*)d_ws;
    float* D  = ws;                                    // 18432 f32
    unsigned short* Mt = (unsigned short*)(ws + 18432); // 16384 bf16
    float* b  = ws + 18432 + 8192;                     // 128 f32

    k1_D<<<dim3(4608), dim3(256), 0, stream>>>(Wsv, W2, D);
    k23_Mb<<<dim3(129), dim3(256), 0, stream>>>(D, W1s, W1v, Wt, Mt, b);
    k4_mfma<<<dim3(256), dim3(256), 0, stream>>>(feat, times, Mt, b, (float*)d_out);
}